// Round 9
// baseline (985.494 us; speedup 1.0000x reference)
//
#include <hip/hip_runtime.h>
#include <hip/hip_bf16.h>
#include <cstdint>
#include <cstddef>

typedef __attribute__((ext_vector_type(4)))  float f32x4;
typedef __attribute__((ext_vector_type(8)))  short s16x8;
typedef __attribute__((ext_vector_type(8)))  unsigned short u16x8;
typedef __attribute__((ext_vector_type(4)))  unsigned short u16x4;
typedef unsigned short ushort_t;
typedef unsigned long long u64;

#define MFMA_BF16(a, b, c) __builtin_amdgcn_mfma_f32_16x16x32_bf16((a), (b), (c), 0, 0, 0)

constexpr int BATCH  = 4;
constexpr int SEQ    = 2048;
constexpr int NHEAD  = 16;
constexpr int HEADD  = 64;
constexpr int HID    = 1024;
constexpr int BH     = BATCH * NHEAD;   // 64

// scale folded into Q projection: 1/sqrt(64) * log2(e)  (softmax in exp2 domain)
#define QSCALE 0.180336880091961f

// fp32 -> bf16 bits, RNE via compiler
__device__ __forceinline__ ushort_t f2bf(float f) {
  return __builtin_bit_cast(ushort_t, __float2bfloat16(f));
}

// Swizzled Ps offset (ushort elems): row stride 136; chunk XOR keeps both the
// scalar write side and the b128 read side <=2-way bank aliased.
__device__ __forceinline__ int ps_off(int q, int k) {       // Ps[q=0..127][k=0..127]
  return q * 136 + ((((k >> 3) ^ ((q >> 3) & 7)) & 15) << 3) + (k & 7);
}

// ---------------------------------------------------------------------------
// Fused projections (z=0,1,2 -> Q,K,V) + mask bit-pack (z=3).
// Q,K out: bf16 [B][H][S][D].  V out: bf16 [B][H][D][S]  (transposed for attn).
// Outputs stored non-temporal. Unchanged from R7 (verified good).
// ---------------------------------------------------------------------------
__global__ __launch_bounds__(256, 2) void proj_fused_kernel(
    const float* __restrict__ q_in, const float* __restrict__ k_in,
    const float* __restrict__ v_in,
    const float* __restrict__ w_q, const float* __restrict__ b_q,
    const float* __restrict__ w_k, const float* __restrict__ b_k,
    const float* __restrict__ w_v, const float* __restrict__ b_v,
    ushort_t* __restrict__ Qp, ushort_t* __restrict__ Kp,
    ushort_t* __restrict__ Vp,
    const int* __restrict__ mask, u64* __restrict__ pm) {
  const int z = blockIdx.z;
  if (z == 3) {
    const int nwords = BATCH * SEQ * SEQ / 64;  // 262144
    const int lane = threadIdx.x & 63;
    int wid = (blockIdx.y * gridDim.x + blockIdx.x) * 4 + (threadIdx.x >> 6);
    const int step = gridDim.x * gridDim.y * 4;
    for (; wid < nwords; wid += step) {
      int mv = __builtin_nontemporal_load(mask + (size_t)wid * 64 + lane);
      u64 bits = __ballot(mv != 0);
      if (lane == 0) pm[wid] = bits;
    }
    return;
  }
  const float* X    = (z == 0) ? q_in : (z == 1) ? k_in : v_in;
  const float* W    = (z == 0) ? w_q : (z == 1) ? w_k : w_v;
  const float* bias = (z == 0) ? b_q : (z == 1) ? b_k : b_v;
  const float scale = (z == 0) ? QSCALE : 1.0f;

  __shared__ ushort_t As[128 * 72];
  __shared__ ushort_t Bs[128 * 72];
  const int tid  = threadIdx.x;
  const int lane = tid & 63;
  const int wave = tid >> 6;
  const int wr = wave >> 1, wc = wave & 1;
  const int lo = lane & 15, hi = lane >> 4;
  const int mb = blockIdx.y, nb = blockIdx.x;

  const int srow = tid >> 4;         // 0..15
  const int scol = (tid & 15) * 4;   // 0..60 (fp32 col)

  f32x4 acc[4][4];
#pragma unroll
  for (int i = 0; i < 4; i++)
#pragma unroll
    for (int j = 0; j < 4; j++) acc[i][j] = (f32x4){0.f, 0.f, 0.f, 0.f};

  const float* xa = X + (size_t)(mb * 128 + srow) * HID + scol;
  const float* xb = W + (size_t)(nb * 128 + srow) * HID + scol;

  for (int k0 = 0; k0 < HID; k0 += 64) {
#pragma unroll
    for (int rr = 0; rr < 128; rr += 16) {
      float4 av = *(const float4*)(xa + (size_t)rr * HID + k0);
      float4 bv = *(const float4*)(xb + (size_t)rr * HID + k0);
      u16x4 a4 = {f2bf(av.x), f2bf(av.y), f2bf(av.z), f2bf(av.w)};
      u16x4 b4 = {f2bf(bv.x), f2bf(bv.y), f2bf(bv.z), f2bf(bv.w)};
      *(u16x4*)(&As[(srow + rr) * 72 + scol]) = a4;
      *(u16x4*)(&Bs[(srow + rr) * 72 + scol]) = b4;
    }
    __syncthreads();
#pragma unroll
    for (int kk = 0; kk < 2; kk++) {
      const int ko = kk * 32 + hi * 8;
      s16x8 af[4], bf[4];
#pragma unroll
      for (int i = 0; i < 4; i++)
        af[i] = *(const s16x8*)(&As[(wr * 64 + i * 16 + lo) * 72 + ko]);
#pragma unroll
      for (int j = 0; j < 4; j++)
        bf[j] = *(const s16x8*)(&Bs[(wc * 64 + j * 16 + lo) * 72 + ko]);
#pragma unroll
      for (int i = 0; i < 4; i++)
#pragma unroll
        for (int j = 0; j < 4; j++)
          acc[i][j] = MFMA_BF16(af[i], bf[j], acc[i][j]);
    }
    __syncthreads();
  }
  if (z != 2) {
    ushort_t* out = (z == 0) ? Qp : Kp;
#pragma unroll
    for (int j = 0; j < 4; j++) {
      const int n = nb * 128 + wc * 64 + j * 16 + lo;
      const float bvn = bias[n];
      const int h = n >> 6, d = n & 63;
#pragma unroll
      for (int i = 0; i < 4; i++) {
        const int m0 = mb * 128 + wr * 64 + i * 16 + hi * 4;
#pragma unroll
        for (int r = 0; r < 4; r++) {
          const int m = m0 + r;
          const int b = m >> 11, s = m & 2047;
          float v = (acc[i][j][r] + bvn) * scale;
          __builtin_nontemporal_store(
              f2bf(v), out + (((size_t)(b * NHEAD + h) * SEQ) + s) * HEADD + d);
        }
      }
    }
  } else {
#pragma unroll
    for (int j = 0; j < 4; j++) {
      const int n = nb * 128 + wc * 64 + j * 16 + lo;
      const float bvn = bias[n];
      const int h = n >> 6, d = n & 63;
#pragma unroll
      for (int i = 0; i < 4; i++) {
        const int m0 = mb * 128 + wr * 64 + i * 16 + hi * 4;
        const int b = m0 >> 11, s0 = m0 & 2047;
        u16x4 pk = {f2bf(acc[i][j][0] + bvn), f2bf(acc[i][j][1] + bvn),
                    f2bf(acc[i][j][2] + bvn), f2bf(acc[i][j][3] + bvn)};
        __builtin_nontemporal_store(
            pk, (u16x4*)(Vp + ((size_t)(b * NHEAD + h) * HEADD + d) * SEQ + s0));
      }
    }
  }
}

// ---------------------------------------------------------------------------
// Fused attention — exact R7 structure (256 thr, 4 waves x 32 q-rows), with
// Vt LDS staging DELETED: PV B-fragments load directly from the transposed
// global V [d][s] (L2-resident; same fragment pattern as the K loads).
// LDS = Ps only (34.8 KB) -> 4 blocks/CU = 16 waves/CU (2x R7's TLP).
// Sweep1: QK^T (K direct from L2), e=exp2(masked s), lrun+=e, Ps<-bf16(e),
//   PV with unnormalized e. End: l=shfl-reduce; ctx=pacc/l (nt); mi=log2(l).
// Sweep2: QK^T recompute, attn=exp2(s-mi) (nt). No LDS, no barriers.
// h-fast within-XCD order keeps 8 K/V panels + shared pm slab L2-resident.
// ---------------------------------------------------------------------------
__global__ __launch_bounds__(256, 4) void fused_attn_kernel(
    const ushort_t* __restrict__ Qp, const ushort_t* __restrict__ Kp,
    const ushort_t* __restrict__ Vtg, const u64* __restrict__ pm,
    float* __restrict__ attn, float* __restrict__ ctx) {
  extern __shared__ ushort_t smem[];
  ushort_t* Ps = smem;           // [128][136] swizzled = 17408 elems = 34816 B

  const int tid  = threadIdx.x;
  const int lane = tid & 63, wave = tid >> 6;
  const int lo = lane & 15, hi = lane >> 4;

  const int f   = blockIdx.x;                 // 0..1023
  const int xcd = f & 7, i5 = f >> 3;         // i5: 0..127
  const int bh  = xcd * 8 + (i5 & 7);
  const int qb  = i5 >> 3;                    // 0..15
  const int b = bh >> 4, h = bh & 15;

  // ---- Q fragments, direct from global (read once) ----
  const ushort_t* Qg = Qp + ((size_t)bh * SEQ + qb * 128 + wave * 32) * HEADD;
  s16x8 aq[2][2];
#pragma unroll
  for (int i = 0; i < 2; i++)
#pragma unroll
    for (int kk = 0; kk < 2; kk++)
      aq[i][kk] = *(const s16x8*)(Qg + (size_t)(i * 16 + lo) * HEADD + kk * 32 + hi * 8);

  const ushort_t* Kg = Kp + (size_t)bh * SEQ * HEADD;          // [s][d]
  const ushort_t* Vg = Vtg + (size_t)bh * HEADD * SEQ;         // [d][s]
  const u64* pmb = pm + (size_t)b * SEQ * 32;
  const int q0 = qb * 128 + wave * 32;

  float lrun[2][4];
#pragma unroll
  for (int i = 0; i < 2; i++)
#pragma unroll
    for (int r = 0; r < 4; r++) lrun[i][r] = 0.f;
  f32x4 pacc[2][4];
#pragma unroll
  for (int i = 0; i < 2; i++)
#pragma unroll
    for (int jd = 0; jd < 4; jd++) pacc[i][jd] = (f32x4){0.f, 0.f, 0.f, 0.f};

  // ================= sweep 1: l + PV (unnormalized) =================
  for (int kt = 0; kt < SEQ / 128; kt++) {
    // QK^T (K fragments direct from global; L2-resident)
    f32x4 sacc[2][8];
#pragma unroll
    for (int i = 0; i < 2; i++)
#pragma unroll
      for (int j = 0; j < 8; j++) sacc[i][j] = (f32x4){0.f, 0.f, 0.f, 0.f};
#pragma unroll
    for (int j = 0; j < 8; j++) {
      const ushort_t* kr = Kg + (size_t)(kt * 128 + j * 16 + lo) * HEADD + hi * 8;
      s16x8 b0 = *(const s16x8*)(kr);
      s16x8 b1 = *(const s16x8*)(kr + 32);
      sacc[0][j] = MFMA_BF16(aq[0][0], b0, sacc[0][j]);
      sacc[1][j] = MFMA_BF16(aq[1][0], b0, sacc[1][j]);
      sacc[0][j] = MFMA_BF16(aq[0][1], b1, sacc[0][j]);
      sacc[1][j] = MFMA_BF16(aq[1][1], b1, sacc[1][j]);
    }

    // e = exp2(masked s); lane-local row partial sums; Ps <- bf16(e)
#pragma unroll
    for (int i = 0; i < 2; i++)
#pragma unroll
      for (int r = 0; r < 4; r++) {
        const int q = q0 + i * 16 + hi * 4 + r;
        const u64* pw = pmb + (size_t)q * 32 + kt * 2;
        u64 s0 = pw[0] >> lo, s1 = pw[1] >> lo;
        const int prow = wave * 32 + i * 16 + hi * 4 + r;
        float tsum = 0.f;
#pragma unroll
        for (int j = 0; j < 8; j++) {
          unsigned bit = (unsigned)((j < 4 ? (s0 >> (j * 16)) : (s1 >> ((j - 4) * 16))) & 1ull);
          float s = bit ? sacc[i][j][r] : -1e30f;
          float ev = __builtin_amdgcn_exp2f(s);
          tsum += ev;
          Ps[ps_off(prow, j * 16 + lo)] = f2bf(ev);
        }
        lrun[i][r] += tsum;
      }
    __syncthreads();   // Ps visible

    // PV: pacc += E @ V  (unnormalized; V B-frags direct from global [d][s])
#pragma unroll
    for (int kkp = 0; kkp < 4; kkp++) {
      const int ko = kkp * 32 + hi * 8;
      s16x8 ap0 = *(const s16x8*)(&Ps[ps_off(wave * 32 + lo, ko)]);
      s16x8 ap1 = *(const s16x8*)(&Ps[ps_off(wave * 32 + 16 + lo, ko)]);
#pragma unroll
      for (int jd = 0; jd < 4; jd++) {
        s16x8 bv = *(const s16x8*)(Vg + (size_t)(jd * 16 + lo) * SEQ + kt * 128 + ko);
        pacc[0][jd] = MFMA_BF16(ap0, bv, pacc[0][jd]);
        pacc[1][jd] = MFMA_BF16(ap1, bv, pacc[1][jd]);
      }
    }
    __syncthreads();   // Ps consumed before next tile's writes
  }

  // ---- finalize l (single shuffle-reduce), ctx = pacc / l (nt) ----
  float il[2][4], mi[2][4];
#pragma unroll
  for (int i = 0; i < 2; i++)
#pragma unroll
    for (int r = 0; r < 4; r++) {
      float l = lrun[i][r];
#pragma unroll
      for (int off = 1; off < 16; off <<= 1) l += __shfl_xor(l, off);
      il[i][r] = 1.0f / l;
      mi[i][r] = __builtin_amdgcn_logf(l);   // log2(l)
    }
#pragma unroll
  for (int i = 0; i < 2; i++)
#pragma unroll
    for (int jd = 0; jd < 4; jd++)
#pragma unroll
      for (int r = 0; r < 4; r++) {
        const int q = q0 + i * 16 + hi * 4 + r;
        __builtin_nontemporal_store(
            pacc[i][jd][r] * il[i][r],
            ctx + ((size_t)b * SEQ + q) * HID + h * HEADD + jd * 16 + lo);
      }

  // ================= sweep 2: attn = exp2(s - log2 l), nt stores ==========
  for (int kt = 0; kt < SEQ / 128; kt++) {
    f32x4 sacc[2][8];
#pragma unroll
    for (int i = 0; i < 2; i++)
#pragma unroll
      for (int j = 0; j < 8; j++) sacc[i][j] = (f32x4){0.f, 0.f, 0.f, 0.f};
#pragma unroll
    for (int j = 0; j < 8; j++) {
      const ushort_t* kr = Kg + (size_t)(kt * 128 + j * 16 + lo) * HEADD + hi * 8;
      s16x8 b0 = *(const s16x8*)(kr);
      s16x8 b1 = *(const s16x8*)(kr + 32);
      sacc[0][j] = MFMA_BF16(aq[0][0], b0, sacc[0][j]);
      sacc[1][j] = MFMA_BF16(aq[1][0], b0, sacc[1][j]);
      sacc[0][j] = MFMA_BF16(aq[0][1], b1, sacc[0][j]);
      sacc[1][j] = MFMA_BF16(aq[1][1], b1, sacc[1][j]);
    }
#pragma unroll
    for (int i = 0; i < 2; i++)
#pragma unroll
      for (int r = 0; r < 4; r++) {
        const int q = q0 + i * 16 + hi * 4 + r;
        const u64* pw = pmb + (size_t)q * 32 + kt * 2;
        u64 s0 = pw[0] >> lo, s1 = pw[1] >> lo;
        const size_t abase = ((size_t)bh * SEQ + q) * SEQ + (size_t)kt * 128;
        const float miv = mi[i][r];
#pragma unroll
        for (int j = 0; j < 8; j++) {
          unsigned bit = (unsigned)((j < 4 ? (s0 >> (j * 16)) : (s1 >> ((j - 4) * 16))) & 1ull);
          float s = bit ? sacc[i][j][r] : -1e30f;
          __builtin_nontemporal_store(__builtin_amdgcn_exp2f(s - miv),
                                      attn + abase + j * 16 + lo);
        }
      }
  }
}

// ---------------------------------------------------------------------------
extern "C" void kernel_launch(void* const* d_in, const int* in_sizes, int n_in,
                              void* d_out, int out_size, void* d_ws, size_t ws_size,
                              hipStream_t stream) {
  const float* query  = (const float*)d_in[0];
  const float* key_in = (const float*)d_in[1];
  const float* value  = (const float*)d_in[2];
  const int*   mask   = (const int*)d_in[3];
  const float* w_q = (const float*)d_in[4];
  const float* b_q = (const float*)d_in[5];
  const float* w_k = (const float*)d_in[6];
  const float* b_k = (const float*)d_in[7];
  const float* w_v = (const float*)d_in[8];
  const float* b_v = (const float*)d_in[9];

  char* ws = (char*)d_ws;
  const size_t proj_elems = (size_t)BATCH * NHEAD * SEQ * HEADD;  // 8388608
  ushort_t* Qp = (ushort_t*)ws;
  ushort_t* Kp = Qp + proj_elems;
  ushort_t* Vp = Kp + proj_elems;          // [B][H][D][S] transposed
  u64* pmask   = (u64*)(ws + 3 * proj_elems * sizeof(ushort_t));

  float* ctx  = (float*)d_out;                         // [B][S][HID]
  float* attn = ctx + (size_t)BATCH * SEQ * HID;       // [B][H][S][S]

  proj_fused_kernel<<<dim3(HID / 128, (BATCH * SEQ) / 128, 4), dim3(256), 0, stream>>>(
      query, key_in, value, w_q, b_q, w_k, b_k, w_v, b_v, Qp, Kp, Vp, mask, pmask);

  const size_t lds_attn = 17408 * sizeof(ushort_t);  // 34816 B (Ps only)
  fused_attn_kernel<<<dim3(BH * (SEQ / 128)), dim3(256), lds_attn, stream>>>(
      Qp, Kp, Vp, pmask, attn, ctx);
}

// Round 10
// 679.692 us; speedup vs baseline: 1.4499x; 1.4499x over previous
//
#include <hip/hip_runtime.h>
#include <hip/hip_bf16.h>
#include <cstdint>
#include <cstddef>

typedef __attribute__((ext_vector_type(4)))  float f32x4;
typedef __attribute__((ext_vector_type(8)))  short s16x8;
typedef __attribute__((ext_vector_type(8)))  unsigned short u16x8;
typedef __attribute__((ext_vector_type(4)))  unsigned short u16x4;
typedef unsigned short ushort_t;
typedef unsigned long long u64;

#define MFMA_BF16(a, b, c) __builtin_amdgcn_mfma_f32_16x16x32_bf16((a), (b), (c), 0, 0, 0)

constexpr int BATCH  = 4;
constexpr int SEQ    = 2048;
constexpr int NHEAD  = 16;
constexpr int HEADD  = 64;
constexpr int HID    = 1024;
constexpr int BH     = BATCH * NHEAD;   // 64
constexpr int MROWS  = BATCH * SEQ;     // 8192

// scale folded at Q epilogue: 1/sqrt(64) * log2(e)  (softmax in exp2 domain)
#define QSCALE 0.180336880091961f

// fp32 -> bf16 bits, RNE via compiler
__device__ __forceinline__ ushort_t f2bf(float f) {
  return __builtin_bit_cast(ushort_t, __float2bfloat16(f));
}

// Swizzled Ps offset (ushort elems): row stride 136; chunk XOR keeps both the
// scalar write side and the b128 read side <=2-way bank aliased.
__device__ __forceinline__ int ps_off(int q, int k) {       // Ps[q=0..127][k=0..127]
  return q * 136 + ((((k >> 3) ^ ((q >> 3) & 7)) & 15) << 3) + (k & 7);
}

// global(16B per lane) -> LDS, wave-uniform LDS base + lane*16
__device__ __forceinline__ void gl2lds16(const ushort_t* g, ushort_t* l) {
  __builtin_amdgcn_global_load_lds(
      (const __attribute__((address_space(1))) void*)g,
      (__attribute__((address_space(3))) void*)l, 16, 0, 0);
}

// ---------------------------------------------------------------------------
// Prepack: z=0,1,2 -> convert X[z] (8.4M f32) and W[z] (1M f32) to bf16 (nt);
// z=3 -> mask bit-pack. Pure streaming.
// ---------------------------------------------------------------------------
__global__ __launch_bounds__(256) void prepack_kernel(
    const float* __restrict__ q_in, const float* __restrict__ k_in,
    const float* __restrict__ v_in,
    const float* __restrict__ w_q, const float* __restrict__ w_k,
    const float* __restrict__ w_v,
    ushort_t* __restrict__ Xb, ushort_t* __restrict__ Wb,
    const int* __restrict__ mask, u64* __restrict__ pm) {
  const int z = blockIdx.z;
  if (z == 3) {
    const int nwords = BATCH * SEQ * SEQ / 64;  // 262144
    const int lane = threadIdx.x & 63;
    int wid = blockIdx.x * 4 + (threadIdx.x >> 6);
    const int step = gridDim.x * 4;
    for (; wid < nwords; wid += step) {
      int mv = __builtin_nontemporal_load(mask + (size_t)wid * 64 + lane);
      u64 bits = __ballot(mv != 0);
      if (lane == 0) pm[wid] = bits;
    }
    return;
  }
  const float* srcX = (z == 0) ? q_in : (z == 1) ? k_in : v_in;
  const float* srcW = (z == 0) ? w_q : (z == 1) ? w_k : w_v;
  ushort_t* dstX = Xb + (size_t)z * MROWS * HID;
  ushort_t* dstW = Wb + (size_t)z * HID * HID;

  const int tid = blockIdx.x * 256 + threadIdx.x;   // 0..131071 (512 blocks)
  const int stride = gridDim.x * 256;

  // X: 8388608 elems = 1048576 vec8 units
  for (int u = tid; u < MROWS * HID / 8; u += stride) {
    const float* s = srcX + (size_t)u * 8;
    f32x4 a = __builtin_nontemporal_load((const f32x4*)s);
    f32x4 b = __builtin_nontemporal_load((const f32x4*)(s + 4));
    u16x8 o = {f2bf(a[0]), f2bf(a[1]), f2bf(a[2]), f2bf(a[3]),
               f2bf(b[0]), f2bf(b[1]), f2bf(b[2]), f2bf(b[3])};
    __builtin_nontemporal_store(o, (u16x8*)(dstX + (size_t)u * 8));
  }
  // W: 1048576 elems = 131072 vec8 units
  for (int u = tid; u < HID * HID / 8; u += stride) {
    const float* s = srcW + (size_t)u * 8;
    f32x4 a = __builtin_nontemporal_load((const f32x4*)s);
    f32x4 b = __builtin_nontemporal_load((const f32x4*)(s + 4));
    u16x8 o = {f2bf(a[0]), f2bf(a[1]), f2bf(a[2]), f2bf(a[3]),
               f2bf(b[0]), f2bf(b[1]), f2bf(b[2]), f2bf(b[3])};
    __builtin_nontemporal_store(o, (u16x8*)(dstW + (size_t)u * 8));
  }
}

// ---------------------------------------------------------------------------
// Proj GEMM, m97-style: bf16 inputs, BK=64, linear [128][64] LDS tiles filled
// via global_load_lds(16B), 4 waves 2x2, 16x16x32 MFMA.
// C[m,n] = (sum_k Xb[m,k]*Wb[n,k] + bias[n]) * scale.
// Epilogue identical to R7: Q,K -> [B][H][S][D]; V -> [B][H][D][S] (nt).
// ---------------------------------------------------------------------------
__global__ __launch_bounds__(256, 4) void proj_gemm_kernel(
    const ushort_t* __restrict__ Xb, const ushort_t* __restrict__ Wb,
    const float* __restrict__ b_q, const float* __restrict__ b_k,
    const float* __restrict__ b_v,
    ushort_t* __restrict__ Qp, ushort_t* __restrict__ Kp,
    ushort_t* __restrict__ Vp) {
  __shared__ ushort_t As[128 * 64];
  __shared__ ushort_t Bs[128 * 64];

  const int z = blockIdx.z;
  const float* bias = (z == 0) ? b_q : (z == 1) ? b_k : b_v;
  const float scale = (z == 0) ? QSCALE : 1.0f;

  const int tid  = threadIdx.x;
  const int lane = tid & 63;
  const int wave = tid >> 6;
  const int wr = wave >> 1, wc = wave & 1;
  const int lo = lane & 15, hi = lane >> 4;
  const int mb = blockIdx.y, nb = blockIdx.x;

  const ushort_t* Ag = Xb + (size_t)z * MROWS * HID + (size_t)mb * 128 * HID;
  const ushort_t* Bg = Wb + (size_t)z * HID * HID + (size_t)nb * 128 * HID;
  // per-lane source offset within a staging chunk: row lane/8, col (lane&7)*8
  const int lrow = lane >> 3, lcol = (lane & 7) * 8;

  f32x4 acc[4][4];
#pragma unroll
  for (int i = 0; i < 4; i++)
#pragma unroll
    for (int j = 0; j < 4; j++) acc[i][j] = (f32x4){0.f, 0.f, 0.f, 0.f};

  for (int k0 = 0; k0 < HID; k0 += 64) {
    // stage A and B tiles: 4 issues x 4 waves x 1KB each per operand
#pragma unroll
    for (int it = 0; it < 4; it++) {
      const int r0 = (it * 4 + wave) * 8;           // 8 rows per wave-issue
      gl2lds16(Ag + (size_t)(r0 + lrow) * HID + k0 + lcol, &As[(it * 4 + wave) * 512]);
      gl2lds16(Bg + (size_t)(r0 + lrow) * HID + k0 + lcol, &Bs[(it * 4 + wave) * 512]);
    }
    __syncthreads();
#pragma unroll
    for (int kk = 0; kk < 2; kk++) {
      const int ko = kk * 32 + hi * 8;
      s16x8 af[4], bf[4];
#pragma unroll
      for (int i = 0; i < 4; i++)
        af[i] = *(const s16x8*)(&As[(wr * 64 + i * 16 + lo) * 64 + ko]);
#pragma unroll
      for (int j = 0; j < 4; j++)
        bf[j] = *(const s16x8*)(&Bs[(wc * 64 + j * 16 + lo) * 64 + ko]);
#pragma unroll
      for (int i = 0; i < 4; i++)
#pragma unroll
        for (int j = 0; j < 4; j++)
          acc[i][j] = MFMA_BF16(af[i], bf[j], acc[i][j]);
    }
    __syncthreads();
  }

  if (z != 2) {
    ushort_t* out = (z == 0) ? Qp : Kp;
#pragma unroll
    for (int j = 0; j < 4; j++) {
      const int n = nb * 128 + wc * 64 + j * 16 + lo;
      const float bvn = bias[n];
      const int h = n >> 6, d = n & 63;
#pragma unroll
      for (int i = 0; i < 4; i++) {
        const int m0 = mb * 128 + wr * 64 + i * 16 + hi * 4;
#pragma unroll
        for (int r = 0; r < 4; r++) {
          const int m = m0 + r;
          const int b = m >> 11, s = m & 2047;
          float v = (acc[i][j][r] + bvn) * scale;
          __builtin_nontemporal_store(
              f2bf(v), Qp == out ? (out + (((size_t)(b * NHEAD + h) * SEQ) + s) * HEADD + d)
                                 : (out + (((size_t)(b * NHEAD + h) * SEQ) + s) * HEADD + d));
        }
      }
    }
  } else {
#pragma unroll
    for (int j = 0; j < 4; j++) {
      const int n = nb * 128 + wc * 64 + j * 16 + lo;
      const float bvn = bias[n];
      const int h = n >> 6, d = n & 63;
#pragma unroll
      for (int i = 0; i < 4; i++) {
        const int m0 = mb * 128 + wr * 64 + i * 16 + hi * 4;
        const int b = m0 >> 11, s0 = m0 & 2047;
        u16x4 pk = {f2bf(acc[i][j][0] + bvn), f2bf(acc[i][j][1] + bvn),
                    f2bf(acc[i][j][2] + bvn), f2bf(acc[i][j][3] + bvn)};
        __builtin_nontemporal_store(
            pk, (u16x4*)(Vp + ((size_t)(b * NHEAD + h) * HEADD + d) * SEQ + s0));
      }
    }
  }
}

// ---------------------------------------------------------------------------
// Fused attention — EXACT R7 (verified best: 723 total; FETCH 59MB optimal).
// ---------------------------------------------------------------------------
__global__ __launch_bounds__(256, 2) void fused_attn_kernel(
    const ushort_t* __restrict__ Qp, const ushort_t* __restrict__ Kp,
    const ushort_t* __restrict__ Vtg, const u64* __restrict__ pm,
    float* __restrict__ attn, float* __restrict__ ctx) {
  extern __shared__ ushort_t smem[];
  ushort_t* Vt = smem;           // [64][136] linear+pad  = 8704 elems
  ushort_t* Ps = smem + 8704;    // [128][136] swizzled   = 17408 elems

  const int tid  = threadIdx.x;
  const int lane = tid & 63, wave = tid >> 6;
  const int lo = lane & 15, hi = lane >> 4;

  const int f   = blockIdx.x;                 // 0..1023
  const int xcd = f & 7, i5 = f >> 3;         // i5: 0..127
  const int bh  = xcd * 8 + (i5 & 7);
  const int qb  = i5 >> 3;                    // 0..15
  const int b = bh >> 4, h = bh & 15;

  const ushort_t* Qg = Qp + ((size_t)bh * SEQ + qb * 128 + wave * 32) * HEADD;
  s16x8 aq[2][2];
#pragma unroll
  for (int i = 0; i < 2; i++)
#pragma unroll
    for (int kk = 0; kk < 2; kk++)
      aq[i][kk] = *(const s16x8*)(Qg + (size_t)(i * 16 + lo) * HEADD + kk * 32 + hi * 8);

  const ushort_t* Kg = Kp + (size_t)bh * SEQ * HEADD;          // [s][d]
  const ushort_t* Vg = Vtg + (size_t)bh * HEADD * SEQ;         // [d][s]
  const u64* pmb = pm + (size_t)b * SEQ * 32;
  const int q0 = qb * 128 + wave * 32;

  float lrun[2][4];
#pragma unroll
  for (int i = 0; i < 2; i++)
#pragma unroll
    for (int r = 0; r < 4; r++) lrun[i][r] = 0.f;
  f32x4 pacc[2][4];
#pragma unroll
  for (int i = 0; i < 2; i++)
#pragma unroll
    for (int jd = 0; jd < 4; jd++) pacc[i][jd] = (f32x4){0.f, 0.f, 0.f, 0.f};

  const int vr16 = tid >> 4;         // 0..15 (V d-row base)
  const int vc8  = (tid & 15) * 8;   // 0..120 (V s-col)

  // ================= sweep 1: l + PV (unnormalized) =================
  for (int kt = 0; kt < SEQ / 128; kt++) {
    u16x8 vreg[4];
#pragma unroll
    for (int it = 0; it < 4; it++)
      vreg[it] = *(const u16x8*)(Vg + (size_t)(it * 16 + vr16) * SEQ + kt * 128 + vc8);

    f32x4 sacc[2][8];
#pragma unroll
    for (int i = 0; i < 2; i++)
#pragma unroll
      for (int j = 0; j < 8; j++) sacc[i][j] = (f32x4){0.f, 0.f, 0.f, 0.f};
#pragma unroll
    for (int j = 0; j < 8; j++) {
      const ushort_t* kr = Kg + (size_t)(kt * 128 + j * 16 + lo) * HEADD + hi * 8;
      s16x8 b0 = *(const s16x8*)(kr);
      s16x8 b1 = *(const s16x8*)(kr + 32);
      sacc[0][j] = MFMA_BF16(aq[0][0], b0, sacc[0][j]);
      sacc[1][j] = MFMA_BF16(aq[1][0], b0, sacc[1][j]);
      sacc[0][j] = MFMA_BF16(aq[0][1], b1, sacc[0][j]);
      sacc[1][j] = MFMA_BF16(aq[1][1], b1, sacc[1][j]);
    }

#pragma unroll
    for (int it = 0; it < 4; it++)
      *(u16x8*)(&Vt[(it * 16 + vr16) * 136 + vc8]) = vreg[it];

#pragma unroll
    for (int i = 0; i < 2; i++)
#pragma unroll
      for (int r = 0; r < 4; r++) {
        const int q = q0 + i * 16 + hi * 4 + r;
        const u64* pw = pmb + (size_t)q * 32 + kt * 2;
        u64 s0 = pw[0] >> lo, s1 = pw[1] >> lo;
        const int prow = wave * 32 + i * 16 + hi * 4 + r;
        float tsum = 0.f;
#pragma unroll
        for (int j = 0; j < 8; j++) {
          unsigned bit = (unsigned)((j < 4 ? (s0 >> (j * 16)) : (s1 >> ((j - 4) * 16))) & 1ull);
          float s = bit ? sacc[i][j][r] : -1e30f;
          float ev = __builtin_amdgcn_exp2f(s);
          tsum += ev;
          Ps[ps_off(prow, j * 16 + lo)] = f2bf(ev);
        }
        lrun[i][r] += tsum;
      }
    __syncthreads();   // Ps + Vt visible

#pragma unroll
    for (int kkp = 0; kkp < 4; kkp++) {
      const int ko = kkp * 32 + hi * 8;
      s16x8 ap0 = *(const s16x8*)(&Ps[ps_off(wave * 32 + lo, ko)]);
      s16x8 ap1 = *(const s16x8*)(&Ps[ps_off(wave * 32 + 16 + lo, ko)]);
#pragma unroll
      for (int jd = 0; jd < 4; jd++) {
        s16x8 bv = *(const s16x8*)(&Vt[(jd * 16 + lo) * 136 + ko]);
        pacc[0][jd] = MFMA_BF16(ap0, bv, pacc[0][jd]);
        pacc[1][jd] = MFMA_BF16(ap1, bv, pacc[1][jd]);
      }
    }
    __syncthreads();   // Ps/Vt consumed before next tile's staging
  }

  float il[2][4], mi[2][4];
#pragma unroll
  for (int i = 0; i < 2; i++)
#pragma unroll
    for (int r = 0; r < 4; r++) {
      float l = lrun[i][r];
#pragma unroll
      for (int off = 1; off < 16; off <<= 1) l += __shfl_xor(l, off);
      il[i][r] = 1.0f / l;
      mi[i][r] = __builtin_amdgcn_logf(l);   // log2(l)
    }
#pragma unroll
  for (int i = 0; i < 2; i++)
#pragma unroll
    for (int jd = 0; jd < 4; jd++)
#pragma unroll
      for (int r = 0; r < 4; r++) {
        const int q = q0 + i * 16 + hi * 4 + r;
        __builtin_nontemporal_store(
            pacc[i][jd][r] * il[i][r],
            ctx + ((size_t)b * SEQ + q) * HID + h * HEADD + jd * 16 + lo);
      }

  // ================= sweep 2: attn = exp2(s - log2 l), nt stores ==========
  for (int kt = 0; kt < SEQ / 128; kt++) {
    f32x4 sacc[2][8];
#pragma unroll
    for (int i = 0; i < 2; i++)
#pragma unroll
      for (int j = 0; j < 8; j++) sacc[i][j] = (f32x4){0.f, 0.f, 0.f, 0.f};
#pragma unroll
    for (int j = 0; j < 8; j++) {
      const ushort_t* kr = Kg + (size_t)(kt * 128 + j * 16 + lo) * HEADD + hi * 8;
      s16x8 b0 = *(const s16x8*)(kr);
      s16x8 b1 = *(const s16x8*)(kr + 32);
      sacc[0][j] = MFMA_BF16(aq[0][0], b0, sacc[0][j]);
      sacc[1][j] = MFMA_BF16(aq[1][0], b0, sacc[1][j]);
      sacc[0][j] = MFMA_BF16(aq[0][1], b1, sacc[0][j]);
      sacc[1][j] = MFMA_BF16(aq[1][1], b1, sacc[1][j]);
    }
#pragma unroll
    for (int i = 0; i < 2; i++)
#pragma unroll
      for (int r = 0; r < 4; r++) {
        const int q = q0 + i * 16 + hi * 4 + r;
        const u64* pw = pmb + (size_t)q * 32 + kt * 2;
        u64 s0 = pw[0] >> lo, s1 = pw[1] >> lo;
        const size_t abase = ((size_t)bh * SEQ + q) * SEQ + (size_t)kt * 128;
        const float miv = mi[i][r];
#pragma unroll
        for (int j = 0; j < 8; j++) {
          unsigned bit = (unsigned)((j < 4 ? (s0 >> (j * 16)) : (s1 >> ((j - 4) * 16))) & 1ull);
          float s = bit ? sacc[i][j][r] : -1e30f;
          __builtin_nontemporal_store(__builtin_amdgcn_exp2f(s - miv),
                                      attn + abase + j * 16 + lo);
        }
      }
  }
}

// ---------------------------------------------------------------------------
extern "C" void kernel_launch(void* const* d_in, const int* in_sizes, int n_in,
                              void* d_out, int out_size, void* d_ws, size_t ws_size,
                              hipStream_t stream) {
  const float* query  = (const float*)d_in[0];
  const float* key_in = (const float*)d_in[1];
  const float* value  = (const float*)d_in[2];
  const int*   mask   = (const int*)d_in[3];
  const float* w_q = (const float*)d_in[4];
  const float* b_q = (const float*)d_in[5];
  const float* w_k = (const float*)d_in[6];
  const float* b_k = (const float*)d_in[7];
  const float* w_v = (const float*)d_in[8];
  const float* b_v = (const float*)d_in[9];

  char* ws = (char*)d_ws;
  const size_t proj_elems = (size_t)BATCH * NHEAD * SEQ * HEADD;  // 8388608
  ushort_t* Qp = (ushort_t*)ws;
  ushort_t* Kp = Qp + proj_elems;
  ushort_t* Vp = Kp + proj_elems;          // [B][H][D][S] transposed
  u64* pmask   = (u64*)(ws + 3 * proj_elems * sizeof(ushort_t));

  float* ctx  = (float*)d_out;                         // [B][S][HID]
  float* attn = ctx + (size_t)BATCH * SEQ * HID;       // [B][H][S][S]

  // bf16 prepack scratch lives in d_out's attn region (1.07 GB): read by the
  // GEMM, overwritten afterwards by the attn kernel. Sequential + deterministic.
  ushort_t* Xb = (ushort_t*)attn;                         // 3 x 8.4M bf16
  ushort_t* Wb = Xb + (size_t)3 * MROWS * HID;            // 3 x 1M bf16

  prepack_kernel<<<dim3(512, 1, 4), dim3(256), 0, stream>>>(
      query, key_in, value, w_q, w_k, w_v, Xb, Wb, mask, pmask);

  proj_gemm_kernel<<<dim3(HID / 128, MROWS / 128, 3), dim3(256), 0, stream>>>(
      Xb, Wb, b_q, b_k, b_v, Qp, Kp, Vp);

  const size_t lds_attn = (8704 + 17408) * sizeof(ushort_t);  // 52224 B
  fused_attn_kernel<<<dim3(BH * (SEQ / 128)), dim3(256), lds_attn, stream>>>(
      Qp, Kp, Vp, pmask, attn, ctx);
}